// Round 10
// baseline (192.880 us; speedup 1.0000x reference)
//
#include <hip/hip_runtime.h>
#include <math.h>

// Problem constants (fixed by the reference)
#define NSEG 32
#define T_DIM 8
#define F_DIM 32
#define P_DIM 8
#define TF 256           // T_DIM * F_DIM
#define OUT_PER_SEG 2048 // T*P*F
#define EPS_DENOM 1e-16f

#define CHUNK 256
#define K2_THREADS 256
#define NPW (CHUNK / 4)   // 4 waves per block, 64 nodes each

// Tiny MLP: h = elu(pos @ W1 + b1) @ W2 + b2  (per node, P=8 outputs)
__device__ __forceinline__ void compute_h(
    float h[P_DIM], const float* __restrict__ pos, int n,
    const float* __restrict__ W1, const float* __restrict__ b1,
    const float* __restrict__ W2, const float* __restrict__ b2) {
  float p0 = pos[3 * n + 0];
  float p1 = pos[3 * n + 1];
  float p2 = pos[3 * n + 2];
  float a[P_DIM];
#pragma unroll
  for (int p = 0; p < P_DIM; p++) {
    float v = b1[p] + p0 * W1[0 * P_DIM + p] + p1 * W1[1 * P_DIM + p] + p2 * W1[2 * P_DIM + p];
    a[p] = v > 0.f ? v : (__expf(v) - 1.f);  // ELU, alpha=1
  }
#pragma unroll
  for (int p = 0; p < P_DIM; p++) {
    float v = b2[p];
#pragma unroll
    for (int j = 0; j < P_DIM; j++) v += a[j] * W2[j * P_DIM + p];
    h[p] = v;
  }
}

// Kernel 0: blocks 0..31 zero the output (boundary-block atomics land in it
// before reduce). Blocks 32..63: per-segment stats -- binary-search bounds and
// the softmax denominator sum(exp(h)) -- precomputed here so reduce_kernel has
// ZERO dependent-load chains (its binary search + MLP pass were an estimated
// 7-22us on 32 mostly-idle blocks).
__global__ __launch_bounds__(256) void zero_stats_kernel(
    float* __restrict__ out, int nf,
    const float* __restrict__ pos, const int* __restrict__ seg,
    const float* __restrict__ W1, const float* __restrict__ b1,
    const float* __restrict__ W2, const float* __restrict__ b2,
    float* __restrict__ invd, int* __restrict__ sbounds, int N) {
  int b = blockIdx.x;
  int tid = threadIdx.x;
  if (b < NSEG) {
    // zero 'out' tile b (exactly 2048 floats per block)
    int i = (b * 256 + tid) * 8;
    if (i + 8 <= nf) {
      float4* o = reinterpret_cast<float4*>(out + i);
      float4 z = make_float4(0.f, 0.f, 0.f, 0.f);
      o[0] = z;
      o[1] = z;
    }
    return;
  }
  int s = b - NSEG;

  __shared__ int bounds[2];
  if (tid < 2) {
    int target = s + tid;
    int lo = 0, hi = N;
    while (lo < hi) {
      int mid = (lo + hi) >> 1;
      if (seg[mid] < target) lo = mid + 1; else hi = mid;
    }
    bounds[tid] = lo;
  }
  __syncthreads();
  int start = bounds[0], end = bounds[1];
  if (tid == 0) {
    sbounds[2 * s] = start;
    sbounds[2 * s + 1] = end;
  }
  if (start >= end) {
    if (tid < P_DIM) invd[s * P_DIM + tid] = 0.f;
    return;
  }

  // denominator: sum of exp(h) over the segment's nodes
  float lsum[P_DIM];
#pragma unroll
  for (int p = 0; p < P_DIM; p++) lsum[p] = 0.f;
  for (int i = start + tid; i < end; i += 256) {
    float h[P_DIM];
    compute_h(h, pos, i, W1, b1, W2, b2);
#pragma unroll
    for (int p = 0; p < P_DIM; p++) lsum[p] += __expf(h[p]);
  }
#pragma unroll
  for (int off = 32; off >= 1; off >>= 1)
#pragma unroll
    for (int p = 0; p < P_DIM; p++)
      lsum[p] += __shfl_down(lsum[p], off, 64);

  __shared__ float wred[P_DIM][4];
  int wid = tid >> 6, lane = tid & 63;
  if (lane == 0) {
#pragma unroll
    for (int p = 0; p < P_DIM; p++) wred[p][wid] = lsum[p];
  }
  __syncthreads();
  if (tid < P_DIM) {
    float ss = wred[tid][0] + wred[tid][1] + wred[tid][2] + wred[tid][3];
    invd[s * P_DIM + tid] = 1.f / (ss + EPS_DENOM);
  }
}

// per-node FMA: acc[p] (float4 over f) += e[p] * x[n, t, f..f+3]
#define FMA_NODE(ii, xv) do {                                                  \
    const float4* _wr = reinterpret_cast<const float4*>(&wbuf[(ii)][0]);       \
    float4 _wa = _wr[0], _wb = _wr[1];                                         \
    acc[0].x += _wa.x*(xv).x; acc[0].y += _wa.x*(xv).y;                        \
    acc[0].z += _wa.x*(xv).z; acc[0].w += _wa.x*(xv).w;                        \
    acc[1].x += _wa.y*(xv).x; acc[1].y += _wa.y*(xv).y;                        \
    acc[1].z += _wa.y*(xv).z; acc[1].w += _wa.y*(xv).w;                        \
    acc[2].x += _wa.z*(xv).x; acc[2].y += _wa.z*(xv).y;                        \
    acc[2].z += _wa.z*(xv).z; acc[2].w += _wa.z*(xv).w;                        \
    acc[3].x += _wa.w*(xv).x; acc[3].y += _wa.w*(xv).y;                        \
    acc[3].z += _wa.w*(xv).z; acc[3].w += _wa.w*(xv).w;                        \
    acc[4].x += _wb.x*(xv).x; acc[4].y += _wb.x*(xv).y;                        \
    acc[4].z += _wb.x*(xv).z; acc[4].w += _wb.x*(xv).w;                        \
    acc[5].x += _wb.y*(xv).x; acc[5].y += _wb.y*(xv).y;                        \
    acc[5].z += _wb.y*(xv).z; acc[5].w += _wb.y*(xv).w;                        \
    acc[6].x += _wb.z*(xv).x; acc[6].y += _wb.z*(xv).y;                        \
    acc[6].z += _wb.z*(xv).z; acc[6].w += _wb.z*(xv).w;                        \
    acc[7].x += _wb.w*(xv).x; acc[7].y += _wb.w*(xv).y;                        \
    acc[7].z += _wb.w*(xv).z; acc[7].w += _wb.w*(xv).w;                        \
  } while (0)

// async DMA one node-row (64 lanes x float4 = 1 KB) into this wave's LDS slot.
// global src is per-lane; LDS dest is wave-uniform base (+ lane*16 by HW).
#define GLL_NODE(node, slot)                                                   \
  __builtin_amdgcn_global_load_lds(                                            \
      (const __attribute__((address_space(1))) void*)(xp + (size_t)(node) * 64),\
      (__attribute__((address_space(3))) void*)(xsl + (slot) * 64),            \
      16, 0, 0)

// flush accumulators via scalar f32 atomics (boundary blocks only; ~15 of 391)
__device__ __forceinline__ void flush_group(float* __restrict__ out, int sg, int c,
                                            float4 acc[P_DIM]) {
  float* o = out + (size_t)sg * OUT_PER_SEG + (c >> 3) * (P_DIM * F_DIM) + (c & 7) * 4;
#pragma unroll
  for (int p = 0; p < P_DIM; p++) {
    float* op = o + p * F_DIM;
    unsafeAtomicAdd(op + 0, acc[p].x);
    unsafeAtomicAdd(op + 1, acc[p].y);
    unsafeAtomicAdd(op + 2, acc[p].z);
    unsafeAtomicAdd(op + 3, acc[p].w);
    acc[p] = make_float4(0.f, 0.f, 0.f, 0.f);
  }
}

// Kernel 1 (byte-identical to r9, the best-measured accum): block = 256
// consecutive nodes, UNNORMALIZED accumulation of exp(h[n,p]) * x[n,t,f].
// Uniform-wave streaming via global_load_lds DMA with counted vmcnt (8 x 1KB
// node-rows in flight per wave). 32KB stage buffer time-shared with the facc
// reduction tile.
__global__ __launch_bounds__(K2_THREADS) void accum_kernel(
    const float* __restrict__ x, const float* __restrict__ pos,
    const int* __restrict__ seg,
    const float* __restrict__ W1, const float* __restrict__ b1,
    const float* __restrict__ W2, const float* __restrict__ b2,
    float* __restrict__ out, float* __restrict__ part,
    int* __restrict__ segtag, int N) {
  __shared__ __align__(16) float wbuf[CHUNK][P_DIM];   // 8 KB
  __shared__ int sbuf[CHUNK];                          // 1 KB
  __shared__ __align__(16) float4 shbuf[2048];         // 32 KB time-shared

  int base = blockIdx.x * CHUNK;
  int cnt = N - base;
  if (cnt > CHUNK) cnt = CHUNK;
  int tid = threadIdx.x;

  // Phase A: e[node][p] = exp(h)
  if (tid < cnt) {
    int n = base + tid;
    sbuf[tid] = seg[n];
    float h[P_DIM];
    compute_h(h, pos, n, W1, b1, W2, b2);
#pragma unroll
    for (int p = 0; p < P_DIM; p++)
      wbuf[tid][p] = __expf(h[p]);
  }
  __syncthreads();

  int c = tid & 63;   // column: t = c>>3, f = (c&7)*4
  int g = tid >> 6;   // wave group, owns nodes [g*64, g*64+64)
  int i0 = g * NPW;
  int i1 = i0 + NPW;
  if (i1 > cnt) i1 = cnt;
  if (i0 > cnt) i0 = cnt;

  const float4* xp = reinterpret_cast<const float4*>(x) + (size_t)base * (TF / 4) + c;

  float4 acc[P_DIM];
#pragma unroll
  for (int p = 0; p < P_DIM; p++) acc[p] = make_float4(0.f, 0.f, 0.f, 0.f);

  bool single = (sbuf[0] == sbuf[cnt - 1]);  // block-uniform
  if (tid == 0) segtag[blockIdx.x] = single ? sbuf[0] : -1;

  if (single) {
    if (i1 - i0 == NPW) {
      // full 64-node wave: DMA-staged stream, 8 node-rows in flight.
      float4* xsl = &shbuf[g * 512];  // this wave's 8-slot stage (8 KB)
#pragma unroll
      for (int j = 0; j < 8; ++j) GLL_NODE(i0 + j, j);
#pragma unroll
      for (int q = 0; q < 14; ++q) {
        asm volatile("s_waitcnt vmcnt(4)" ::: "memory");
        __builtin_amdgcn_sched_barrier(0);
        int ss = (q & 1) * 4;          // slot base (quads alternate halves)
        int nb = i0 + q * 4;           // node base
#pragma unroll
        for (int j = 0; j < 4; ++j) {
          float4 xv = xsl[(ss + j) * 64 + c];
          FMA_NODE(nb + j, xv);
        }
#pragma unroll
        for (int j = 0; j < 4; ++j) GLL_NODE(i0 + (q + 2) * 4 + j, ss + j);
      }
      asm volatile("s_waitcnt vmcnt(4)" ::: "memory");
      __builtin_amdgcn_sched_barrier(0);
#pragma unroll
      for (int j = 0; j < 4; ++j) {
        float4 xv = xsl[(0 + j) * 64 + c];
        FMA_NODE(i0 + 56 + j, xv);
      }
      asm volatile("s_waitcnt vmcnt(0)" ::: "memory");
      __builtin_amdgcn_sched_barrier(0);
#pragma unroll
      for (int j = 0; j < 4; ++j) {
        float4 xv = xsl[(4 + j) * 64 + c];
        FMA_NODE(i0 + 60 + j, xv);
      }
    } else {
      // tail wave of the last block: plain loads
      int i = i0;
      for (; i + 8 <= i1; i += 8) {
        float4 xv[8];
#pragma unroll
        for (int j = 0; j < 8; j++) xv[j] = xp[(size_t)(i + j) * (TF / 4)];
#pragma unroll
        for (int j = 0; j < 8; j++) FMA_NODE(i + j, xv[j]);
      }
      for (; i < i1; ++i) {
        float4 xv = xp[(size_t)i * (TF / 4)];
        FMA_NODE(i, xv);
      }
    }

    // all waves' DMA consumed; xstage is dead -> reuse as facc
    __syncthreads();
#pragma unroll
    for (int p = 0; p < P_DIM; p++) shbuf[p * 256 + g * 64 + c] = acc[p];
    __syncthreads();

    int t = tid >> 5;
    int p = (tid >> 2) & 7;
    int fb = tid & 3;
    int c0 = t * 8 + fb * 2;
    float4 A = shbuf[p * 256 + 0 * 64 + c0];
    float4 B = shbuf[p * 256 + 0 * 64 + c0 + 1];
#pragma unroll
    for (int gg = 1; gg < 4; gg++) {
      float4 a2 = shbuf[p * 256 + gg * 64 + c0];
      float4 b2v = shbuf[p * 256 + gg * 64 + c0 + 1];
      A.x += a2.x;  A.y += a2.y;  A.z += a2.z;  A.w += a2.w;
      B.x += b2v.x; B.y += b2v.y; B.z += b2v.z; B.w += b2v.w;
    }
    int off = t * (P_DIM * F_DIM) + p * F_DIM + fb * 8;
    float4* po = reinterpret_cast<float4*>(part + (size_t)blockIdx.x * OUT_PER_SEG + off);
    po[0] = A;
    po[1] = B;
  } else {
    // Slow path: chunk spans segment boundaries (~15 of 391 blocks).
    int i = i0;
    while (i < i1) {
      int cur = sbuf[i];
      int j = i + 1;
      while (j < i1 && sbuf[j] == cur) j++;
      int k = i;
      for (; k + 4 <= j; k += 4) {
        float4 xv0 = xp[(size_t)(k + 0) * (TF / 4)];
        float4 xv1 = xp[(size_t)(k + 1) * (TF / 4)];
        float4 xv2 = xp[(size_t)(k + 2) * (TF / 4)];
        float4 xv3 = xp[(size_t)(k + 3) * (TF / 4)];
        FMA_NODE(k + 0, xv0);
        FMA_NODE(k + 1, xv1);
        FMA_NODE(k + 2, xv2);
        FMA_NODE(k + 3, xv3);
      }
      for (; k < j; ++k) {
        float4 xv = xp[(size_t)k * (TF / 4)];
        FMA_NODE(k, xv);
      }
      flush_group(out, cur, c, acc);
      i = j;
    }
  }
}

// Kernel 2: one block per segment. No binary search, no MLP pass -- reads
// precomputed bounds + inverse denominators, scans ~13 tags, combines tagged
// partials + boundary atomic contributions, scales, stores.
__global__ __launch_bounds__(256) void reduce_kernel(
    const int* __restrict__ segtag, const float* __restrict__ part,
    const float* __restrict__ invd, const int* __restrict__ sbounds,
    float* __restrict__ out) {
  int s = blockIdx.x;
  int tid = threadIdx.x;

  int start = sbounds[2 * s];
  int end = sbounds[2 * s + 1];
  if (start >= end) return;  // empty segment: out stays zero

  int b0 = start / CHUNK;
  int b1i = (end - 1) / CHUNK;
  int p = (tid >> 2) & 7;  // out layout: [t][p][f], tid*8 = t*256 + p*32 + fb*8
  float s0 = invd[s * P_DIM + p];

  float* o = out + (size_t)s * OUT_PER_SEG + tid * 8;
  float4 A = reinterpret_cast<float4*>(o)[0];  // boundary atomics
  float4 B = reinterpret_cast<float4*>(o)[1];
  for (int b = b0; b <= b1i; b++) {
    if (segtag[b] == s) {
      const float4* pp = reinterpret_cast<const float4*>(
          part + (size_t)b * OUT_PER_SEG + tid * 8);
      float4 a2 = pp[0], b2v = pp[1];
      A.x += a2.x;  A.y += a2.y;  A.z += a2.z;  A.w += a2.w;
      B.x += b2v.x; B.y += b2v.y; B.z += b2v.z; B.w += b2v.w;
    }
  }
  A.x *= s0; A.y *= s0; A.z *= s0; A.w *= s0;
  B.x *= s0; B.y *= s0; B.z *= s0; B.w *= s0;
  reinterpret_cast<float4*>(o)[0] = A;
  reinterpret_cast<float4*>(o)[1] = B;
}

extern "C" void kernel_launch(void* const* d_in, const int* in_sizes, int n_in,
                              void* d_out, int out_size, void* d_ws, size_t ws_size,
                              hipStream_t stream) {
  const float* pos = (const float*)d_in[0];
  const float* x   = (const float*)d_in[1];
  const int*   seg = (const int*)d_in[2];
  const float* W1  = (const float*)d_in[3];
  const float* b1  = (const float*)d_in[4];
  const float* W2  = (const float*)d_in[5];
  const float* b2  = (const float*)d_in[6];
  float* out = (float*)d_out;
  int N = in_sizes[2];
  int nblk = (N + CHUNK - 1) / CHUNK;

  // workspace layout: segtag [nblk i32] | sbounds [64 i32] | invd [256 f32]
  //                 | partials [nblk*2048 f32]
  char* ws = (char*)d_ws;
  size_t off_sb = ((size_t)nblk * 4 + 255) & ~(size_t)255;
  size_t off_iv = (off_sb + 2 * NSEG * 4 + 255) & ~(size_t)255;
  size_t off_pt = (off_iv + NSEG * P_DIM * 4 + 255) & ~(size_t)255;
  int*   segtag  = (int*)ws;
  int*   sbounds = (int*)(ws + off_sb);
  float* invd    = (float*)(ws + off_iv);
  float* part    = (float*)(ws + off_pt);

  int zblk = (out_size / 8 + 255) / 256;  // 32 for this problem
  zero_stats_kernel<<<zblk + NSEG, 256, 0, stream>>>(
      out, out_size, pos, seg, W1, b1, W2, b2, invd, sbounds, N);

  accum_kernel<<<nblk, K2_THREADS, 0, stream>>>(
      x, pos, seg, W1, b1, W2, b2, out, part, segtag, N);

  reduce_kernel<<<NSEG, 256, 0, stream>>>(
      segtag, part, invd, sbounds, out);
}